// Round 1
// baseline (3954.372 us; speedup 1.0000x reference)
//
#include <hip/hip_runtime.h>

#define NN 100000
#define NE 1600000
#define DIM 128
#define LDH 132   // padded LDS leading dim (breaks power-of-2 bank strides)

// ---------------------------------------------------------------------------
// ws layout: [0..255] int flag area (flag[0] = OR of odd index words),
//            [256 ...] msg float[NN*DIM]
// ---------------------------------------------------------------------------

// Detect whether edge_index is stored as int64 (odd 32-bit words of the first
// row are all zero) or int32. Writes OR of odd words into orflag[0].
__global__ void detect_kernel(const int* __restrict__ idx32, int* __restrict__ orflag) {
    int acc = 0;
    int i = blockIdx.x * blockDim.x + threadIdx.x;
    const int stride = gridDim.x * blockDim.x;
    for (; i < NE; i += stride) acc |= idx32[2 * i + 1];
#pragma unroll
    for (int m = 32; m >= 1; m >>= 1) acc |= __shfl_xor(acc, m);
    if ((threadIdx.x & 63) == 0 && acc != 0) atomicOr(orflag, 1);
}

// Scatter-add edge features onto destination nodes.
// Block = 256 threads = 8 edges x 32 float4-chunks. Fully coalesced reads.
__global__ void scatter_kernel(const float4* __restrict__ e4,
                               const int* __restrict__ idx32,
                               const int* __restrict__ orflag,
                               float* __restrict__ msg) {
    const int t = threadIdx.x;
    const int edge = blockIdx.x * 8 + (t >> 5);
    const int c4 = t & 31;
    const int is64 = (orflag[0] == 0);
    int dst;
    if (is64) dst = idx32[2 * (NE + edge)];      // low word of int64
    else      dst = idx32[NE + edge];
    float4 v = e4[(size_t)edge * 32 + c4];
    float* m = msg + (size_t)dst * DIM + c4 * 4;
    unsafeAtomicAdd(m + 0, v.x);
    unsafeAtomicAdd(m + 1, v.y);
    unsafeAtomicAdd(m + 2, v.z);
    unsafeAtomicAdd(m + 3, v.w);
}

// acc[ii][jj] += sum_k in[n0+ii][k] * W[k][j0+jj]   (in = LDS tile, W = global)
__device__ __forceinline__ void gemm_acc(const float* __restrict__ in,
                                         const float* __restrict__ W,
                                         float acc[4][4], int n0, int j0) {
#pragma unroll 4
    for (int k = 0; k < DIM; k += 4) {
        float4 w0 = *(const float4*)(W + (size_t)(k + 0) * DIM + j0);
        float4 w1 = *(const float4*)(W + (size_t)(k + 1) * DIM + j0);
        float4 w2 = *(const float4*)(W + (size_t)(k + 2) * DIM + j0);
        float4 w3 = *(const float4*)(W + (size_t)(k + 3) * DIM + j0);
#pragma unroll
        for (int ii = 0; ii < 4; ++ii) {
            float4 h = *(const float4*)(in + (n0 + ii) * LDH + k);
            acc[ii][0] += h.x * w0.x + h.y * w1.x + h.z * w2.x + h.w * w3.x;
            acc[ii][1] += h.x * w0.y + h.y * w1.y + h.z * w2.y + h.w * w3.y;
            acc[ii][2] += h.x * w0.z + h.y * w1.z + h.z * w2.z + h.w * w3.z;
            acc[ii][3] += h.x * w0.w + h.y * w1.w + h.z * w2.w + h.w * w3.w;
        }
    }
}

// Fused: concat-GEMM(W0) -> relu -> 2x hidden -> output -> GroupNorm -> +x
// One block = 32 nodes. h tiles live in LDS the whole time.
__global__ void __launch_bounds__(256)
mlp_kernel(const float* __restrict__ x, const float* __restrict__ msg,
           const float* __restrict__ W0, const float* __restrict__ b0,
           const float* __restrict__ Wh, const float* __restrict__ bh,
           const float* __restrict__ Wo, const float* __restrict__ bo,
           const float* __restrict__ gnw, const float* __restrict__ gnb,
           float* __restrict__ out) {
    __shared__ __align__(16) float xs[32][LDH];
    __shared__ __align__(16) float hA[32][LDH];
    __shared__ __align__(16) float mB[32][LDH];  // msg tile, later reused as hB

    const int t = threadIdx.x;
    const int nodeBase = blockIdx.x * 32;

    // Stage x and msg tiles (32 nodes x 128 ch), coalesced float4.
#pragma unroll
    for (int i = 0; i < 4; ++i) {
        int flat = t + i * 256;          // 0..1023
        int r = flat >> 5;
        int c = (flat & 31) * 4;
        *(float4*)&xs[r][c] = *(const float4*)(x + (size_t)(nodeBase + r) * DIM + c);
        *(float4*)&mB[r][c] = *(const float4*)(msg + (size_t)(nodeBase + r) * DIM + c);
    }
    __syncthreads();

    const int n0 = (t & 7) * 4;
    const int j0 = (t >> 3) * 4;
    float acc[4][4];

    // ---- layer 0: relu([x|msg] @ W0 + b0) -> hA
    {
        float4 bv = *(const float4*)(b0 + j0);
#pragma unroll
        for (int ii = 0; ii < 4; ++ii) {
            acc[ii][0] = bv.x; acc[ii][1] = bv.y; acc[ii][2] = bv.z; acc[ii][3] = bv.w;
        }
        gemm_acc(&xs[0][0], W0, acc, n0, j0);
        gemm_acc(&mB[0][0], W0 + (size_t)DIM * DIM, acc, n0, j0);
        __syncthreads();  // mB fully consumed before overwrite as hB
#pragma unroll
        for (int ii = 0; ii < 4; ++ii)
#pragma unroll
            for (int jj = 0; jj < 4; ++jj)
                hA[n0 + ii][j0 + jj] = fmaxf(acc[ii][jj], 0.0f);
    }
    __syncthreads();

    // ---- layer 1: relu(hA @ Wh[0] + bh[0]) -> mB(=hB)
    {
        float4 bv = *(const float4*)(bh + j0);
#pragma unroll
        for (int ii = 0; ii < 4; ++ii) {
            acc[ii][0] = bv.x; acc[ii][1] = bv.y; acc[ii][2] = bv.z; acc[ii][3] = bv.w;
        }
        gemm_acc(&hA[0][0], Wh, acc, n0, j0);
        __syncthreads();
#pragma unroll
        for (int ii = 0; ii < 4; ++ii)
#pragma unroll
            for (int jj = 0; jj < 4; ++jj)
                mB[n0 + ii][j0 + jj] = fmaxf(acc[ii][jj], 0.0f);
    }
    __syncthreads();

    // ---- layer 2: relu(hB @ Wh[1] + bh[1]) -> hA
    {
        float4 bv = *(const float4*)(bh + DIM + j0);
#pragma unroll
        for (int ii = 0; ii < 4; ++ii) {
            acc[ii][0] = bv.x; acc[ii][1] = bv.y; acc[ii][2] = bv.z; acc[ii][3] = bv.w;
        }
        gemm_acc(&mB[0][0], Wh + (size_t)DIM * DIM, acc, n0, j0);
        __syncthreads();
#pragma unroll
        for (int ii = 0; ii < 4; ++ii)
#pragma unroll
            for (int jj = 0; jj < 4; ++jj)
                hA[n0 + ii][j0 + jj] = fmaxf(acc[ii][jj], 0.0f);
    }
    __syncthreads();

    // ---- layer 3 (output): hA @ Wo + bo -> mB(=h3), no relu
    {
        float4 bv = *(const float4*)(bo + j0);
#pragma unroll
        for (int ii = 0; ii < 4; ++ii) {
            acc[ii][0] = bv.x; acc[ii][1] = bv.y; acc[ii][2] = bv.z; acc[ii][3] = bv.w;
        }
        gemm_acc(&hA[0][0], Wo, acc, n0, j0);
        __syncthreads();
#pragma unroll
        for (int ii = 0; ii < 4; ++ii)
#pragma unroll
            for (int jj = 0; jj < 4; ++jj)
                mB[n0 + ii][j0 + jj] = acc[ii][jj];
    }
    __syncthreads();

    // ---- GroupNorm(1 group over 128 ch) + residual, write out.
    // 8 threads per node, 16 channels each; lanes of a node group are
    // consecutive & 8-aligned -> shfl_xor reduction stays in-group.
    {
        const int n = t >> 3;
        const int c0 = (t & 7) * 16;
        float s = 0.0f, s2 = 0.0f;
#pragma unroll
        for (int c = 0; c < 16; ++c) {
            float v = mB[n][c0 + c];
            s += v; s2 += v * v;
        }
#pragma unroll
        for (int m = 1; m < 8; m <<= 1) {
            s  += __shfl_xor(s, m);
            s2 += __shfl_xor(s2, m);
        }
        const float mean = s * (1.0f / 128.0f);
        float var = s2 * (1.0f / 128.0f) - mean * mean;
        var = fmaxf(var, 0.0f);
        const float rs = rsqrtf(var + 1e-5f);
#pragma unroll
        for (int c = 0; c < 16; c += 4) {
            int cc = c0 + c;
            float4 gw = *(const float4*)(gnw + cc);
            float4 gb = *(const float4*)(gnb + cc);
            float4 hv = *(const float4*)&mB[n][cc];
            float4 xv = *(const float4*)&xs[n][cc];
            float4 o;
            o.x = xv.x + (hv.x - mean) * rs * gw.x + gb.x;
            o.y = xv.y + (hv.y - mean) * rs * gw.y + gb.y;
            o.z = xv.z + (hv.z - mean) * rs * gw.z + gb.z;
            o.w = xv.w + (hv.w - mean) * rs * gw.w + gb.w;
            *(float4*)(out + (size_t)(nodeBase + n) * DIM + cc) = o;
        }
    }
}

extern "C" void kernel_launch(void* const* d_in, const int* in_sizes, int n_in,
                              void* d_out, int out_size, void* d_ws, size_t ws_size,
                              hipStream_t stream) {
    const float* x   = (const float*)d_in[0];
    const float* e   = (const float*)d_in[1];
    const int*   idx = (const int*)d_in[2];
    const float* W0  = (const float*)d_in[3];
    const float* b0  = (const float*)d_in[4];
    const float* Wh  = (const float*)d_in[5];
    const float* bh  = (const float*)d_in[6];
    const float* Wo  = (const float*)d_in[7];
    const float* bo  = (const float*)d_in[8];
    const float* gnw = (const float*)d_in[9];
    const float* gnb = (const float*)d_in[10];
    float* out = (float*)d_out;

    int*   flag = (int*)d_ws;
    float* msg  = (float*)((char*)d_ws + 256);

    // Zero flag + msg accumulator (ws is poisoned 0xAA before every call).
    hipMemsetAsync(d_ws, 0, 256 + (size_t)NN * DIM * sizeof(float), stream);

    detect_kernel<<<512, 256, 0, stream>>>(idx, flag);
    scatter_kernel<<<NE / 8, 256, 0, stream>>>((const float4*)e, idx, flag, msg);
    mlp_kernel<<<NN / 32, 256, 0, stream>>>(x, msg, W0, b0, Wh, bh, Wo, bo,
                                            gnw, gnb, out);
}